// Round 8
// baseline (167.411 us; speedup 1.0000x reference)
//
#include <hip/hip_runtime.h>

#define NB 2
#define NH 8
#define NS 2048
#define ND 64
#define QBLK 64
#define KBLK 64
#define NT (NS / KBLK)    // 32
#define QST 68            // Q LDS row stride (f16)
#define KST 76            // K LDS row stride
#define VST 70            // VT row stride
#define PST 68            // P row stride

typedef _Float16 f16x4 __attribute__((ext_vector_type(4)));
typedef _Float16 f16x8 __attribute__((ext_vector_type(8)));
typedef float    f32x4 __attribute__((ext_vector_type(4)));

#define MFMA16(A,B,C) __builtin_amdgcn_mfma_f32_16x16x32_f16((A),(B),(C),0,0,0)

static __device__ __forceinline__ f16x8 cat8(f16x4 a, f16x4 b) {
    return __builtin_shufflevector(a, b, 0, 1, 2, 3, 4, 5, 6, 7);
}
static __device__ __forceinline__ f16x8 lds8(const _Float16* p) {
    f16x4 a = *(const f16x4*)p;          // ds_read_b64 pair
    f16x4 b = *(const f16x4*)(p + 4);
    return cat8(a, b);
}
// dbuf barrier: my LDS ops drained, rendezvous; no vmcnt drain
static __device__ __forceinline__ void barw() {
    asm volatile("s_waitcnt lgkmcnt(0)" ::: "memory");
    __builtin_amdgcn_sched_barrier(0);
    __builtin_amdgcn_s_barrier();
    __builtin_amdgcn_sched_barrier(0);
}

__global__ __launch_bounds__(256, 2)
void sdpa_kernel(const float* __restrict__ Qg, const float* __restrict__ Kg,
                 const float* __restrict__ Vg, float* __restrict__ Og,
                 float* __restrict__ Ag)
{
    const int tid  = threadIdx.x;
    const int w    = tid >> 6;
    const int lane = tid & 63;
    const int lg   = lane >> 4;
    const int lc   = lane & 15;

    // XCD-pinned decode (proven: FETCH 103->12 MB): bid&7 = XCD, 2 heads/XCD.
    const int bid = blockIdx.x;
    const int xcd = bid & 7;
    const int j   = bid >> 3;           // 0..63
    const int bh  = 2 * xcd + (j >> 5); // 0..15
    const int qt  = j & 31;             // 0..31

    const size_t base = (size_t)bh * NS * ND;
    const float* Qp = Qg + base + (size_t)qt * QBLK * ND;
    const float* Kp = Kg + base;
    const float* Vp = Vg + base;
    float*       Op = Og + base + (size_t)qt * QBLK * ND;
    float*       Ap = Ag + (size_t)bh * NS * NS + (size_t)qt * QBLK * NS;

    // pool: Ks0 9728 | Ks1 9728 | VT0 8960 | VT1 8960 | union(Qs,Ps) 8704 = 46080 B
    __shared__ __align__(16) unsigned char pool[46080];
    _Float16* Ks0 = (_Float16*)pool;
    _Float16* Ks1 = (_Float16*)(pool + 9728);
    _Float16* VT0 = (_Float16*)(pool + 19456);
    _Float16* VT1 = (_Float16*)(pool + 28416);
    _Float16* Qs  = (_Float16*)(pool + 37376);   // dead after qf loads
    _Float16* Ps  = (_Float16*)(pool + 37376);   // overlays Qs in pass B

    const int srow = tid >> 4;          // 0..15
    const int sd0  = (tid & 15) * 4;    // 0..60
    const int kq2  = tid >> 4;          // 0..15 (V: key quad 4*kq2)
    const int dg2  = tid & 15;          // 0..15 (V: d quad 4*dg2)

    // ---- stage Q (scaled by 1/T = 1/8, exact) ----
    #pragma unroll
    for (int it = 0; it < 4; ++it) {
        const int r = srow + 16 * it;
        float4 f = *(const float4*)&Qp[(size_t)r * ND + sd0];
        f16x4 h = { (_Float16)(f.x * 0.125f), (_Float16)(f.y * 0.125f),
                    (_Float16)(f.z * 0.125f), (_Float16)(f.w * 0.125f) };
        *(f16x4*)&Qs[r * QST + sd0] = h;
    }
    __syncthreads();

    const int q = 16 * w + lc;
    const f16x8 qf0 = lds8(&Qs[q * QST + 8 * lg]);
    const f16x8 qf1 = lds8(&Qs[q * QST + 8 * lg + 32]);
    __syncthreads();   // Qs reads done before Ps overlay (pass B)

    float4 kha[4], khb[4], vha[4], vhb[4];

    auto loadK = [&](float4 (&d)[4], int t) {
        #pragma unroll
        for (int it = 0; it < 4; ++it)
            d[it] = *(const float4*)&Kp[(size_t)(t * KBLK + srow + 16 * it) * ND + sd0];
    };
    auto writeK = [&](const float4 (&s)[4], _Float16* ks) {
        #pragma unroll
        for (int it = 0; it < 4; ++it) {
            f16x4 h = { (_Float16)s[it].x, (_Float16)s[it].y,
                        (_Float16)s[it].z, (_Float16)s[it].w };
            *(f16x4*)&ks[(srow + 16 * it) * KST + sd0] = h;
        }
    };
    auto loadV = [&](float4 (&d)[4], int t) {   // rows 4kq2..+3, d 4dg2..+3
        #pragma unroll
        for (int r = 0; r < 4; ++r)
            d[r] = *(const float4*)&Vp[(size_t)(t * KBLK + 4 * kq2 + r) * ND + 4 * dg2];
    };
    auto writeVT = [&](const float4 (&s)[4], _Float16* vt) { // 4x4 reg transpose
        #pragma unroll
        for (int jj = 0; jj < 4; ++jj) {
            f16x4 col = { (_Float16)s[0][jj], (_Float16)s[1][jj],
                          (_Float16)s[2][jj], (_Float16)s[3][jj] };
            *(f16x4*)&vt[(4 * dg2 + jj) * VST + 4 * kq2] = col;
        }
    };

    float lacc = 0.0f;   // max-free softmax: per-lane partial sum of exp(s)

    auto computeA = [&](const _Float16* ks) {
        f32x4 s[4];
        __builtin_amdgcn_s_setprio(1);
        #pragma unroll
        for (int mt = 0; mt < 4; ++mt) {
            f16x8 a0 = lds8(&ks[(16 * mt + lc) * KST + 8 * lg]);
            f16x8 a1 = lds8(&ks[(16 * mt + lc) * KST + 8 * lg + 32]);
            f32x4 z = {0.f, 0.f, 0.f, 0.f};
            z = MFMA16(a0, qf0, z);
            z = MFMA16(a1, qf1, z);
            s[mt] = z;
        }
        __builtin_amdgcn_s_setprio(0);
        #pragma unroll
        for (int mt = 0; mt < 4; ++mt)
            #pragma unroll
            for (int r = 0; r < 4; ++r)
                lacc += __expf(s[mt][r]);
    };

    // ============ PASS A: denominator (1 barrier/phase, write-first order) ============
    loadK(kha, 0);
    writeK(kha, Ks0);
    loadK(kha, 1);
    barw();                            // Ks0 ready; kha holds tile 1
    for (int t = 0; t < NT; t += 2) {
        writeK(kha, Ks1);              // stage t+1 (write FIRST: no store-drain)
        loadK(khb, t + 2 < NT ? t + 2 : 0);
        computeA(Ks0);                 // consume t
        barw();
        writeK(khb, Ks0);              // stage t+2
        loadK(kha, t + 3 < NT ? t + 3 : 0);
        computeA(Ks1);                 // consume t+1
        barw();
    }
    lacc += __shfl_xor(lacc, 16);
    lacc += __shfl_xor(lacc, 32);
    const float il = 1.0f / lacc;

    // ============ PASS B: attn write + PV ============
    f32x4 acc[4];
    #pragma unroll
    for (int dt = 0; dt < 4; ++dt) acc[dt] = {0.f, 0.f, 0.f, 0.f};

    auto computeB = [&](const _Float16* ks, const _Float16* vt, int t) {
        f32x4 s[4];
        __builtin_amdgcn_s_setprio(1);
        #pragma unroll
        for (int mt = 0; mt < 4; ++mt) {
            f16x8 a0 = lds8(&ks[(16 * mt + lc) * KST + 8 * lg]);
            f16x8 a1 = lds8(&ks[(16 * mt + lc) * KST + 8 * lg + 32]);
            f32x4 z = {0.f, 0.f, 0.f, 0.f};
            z = MFMA16(a0, qf0, z);
            z = MFMA16(a1, qf1, z);
            s[mt] = z;
        }
        __builtin_amdgcn_s_setprio(0);
        #pragma unroll
        for (int mt = 0; mt < 4; ++mt) {
            f32x4 p;
            #pragma unroll
            for (int r = 0; r < 4; ++r)
                p[r] = __expf(s[mt][r]) * il;
            __builtin_nontemporal_store(
                p, (f32x4*)&Ap[(size_t)q * NS + t * KBLK + 16 * mt + 4 * lg]);
            f16x4 ph = { (_Float16)p[0], (_Float16)p[1],
                         (_Float16)p[2], (_Float16)p[3] };
            *(f16x4*)&Ps[q * PST + 16 * mt + 4 * lg] = ph;
        }
        asm volatile("s_waitcnt lgkmcnt(0)" ::: "memory");  // wave-private P rows
        __builtin_amdgcn_sched_barrier(0);
        f16x8 bf0 = lds8(&Ps[q * PST + 8 * lg]);
        f16x8 bf1 = lds8(&Ps[q * PST + 32 + 8 * lg]);
        __builtin_amdgcn_s_setprio(1);
        #pragma unroll
        for (int dt = 0; dt < 4; ++dt) {
            f16x8 af0 = lds8(&vt[(16 * dt + lc) * VST + 8 * lg]);
            f16x8 af1 = lds8(&vt[(16 * dt + lc) * VST + 32 + 8 * lg]);
            acc[dt] = MFMA16(af0, bf0, acc[dt]);
            acc[dt] = MFMA16(af1, bf1, acc[dt]);
        }
        __builtin_amdgcn_s_setprio(0);
    };

    loadK(kha, 0); loadV(vha, 0);
    writeK(kha, Ks0); writeVT(vha, VT0);
    loadK(kha, 1); loadV(vha, 1);
    barw();                            // Ks0/VT0 ready; kha/vha hold tile 1
    for (int t = 0; t < NT; t += 2) {
        writeK(kha, Ks1); writeVT(vha, VT1);     // stage t+1 (write FIRST)
        { const int n = t + 2 < NT ? t + 2 : 0; loadK(khb, n); loadV(vhb, n); }
        computeB(Ks0, VT0, t);                   // consume t (stores at end)
        barw();
        writeK(khb, Ks0); writeVT(vhb, VT0);     // stage t+2
        { const int n = t + 3 < NT ? t + 3 : 0; loadK(kha, n); loadV(vha, n); }
        computeB(Ks1, VT1, t + 1);               // consume t+1
        barw();
    }

    // O^T[d = 16dt+4lg+r][q] -> Op[q][d]
    #pragma unroll
    for (int dt = 0; dt < 4; ++dt)
        __builtin_nontemporal_store(
            acc[dt], (f32x4*)&Op[(size_t)q * ND + 16 * dt + 4 * lg]);
}

extern "C" void kernel_launch(void* const* d_in, const int* in_sizes, int n_in,
                              void* d_out, int out_size, void* d_ws, size_t ws_size,
                              hipStream_t stream) {
    const float* q = (const float*)d_in[0];
    const float* k = (const float*)d_in[1];
    const float* v = (const float*)d_in[2];
    float* out  = (float*)d_out;
    float* attn = out + (size_t)NB * NH * NS * ND;  // outputs: (output, attn)

    sdpa_kernel<<<dim3((NS / QBLK) * NB * NH), 256, 0, stream>>>(q, k, v, out, attn);
}

// Round 9
// 110.529 us; speedup vs baseline: 1.5146x; 1.5146x over previous
//
#include <hip/hip_runtime.h>

#define NB 2
#define NH 8
#define NS 2048
#define ND 64
#define QBLK 64
#define KBLK 128
#define NKT (NS / KBLK)   // 16
#define QST 76            // Q/K LDS row stride (f16)
#define KST 76
#define VST 140           // VT row stride
#define PST 132           // P row stride

typedef _Float16 f16x4 __attribute__((ext_vector_type(4)));
typedef _Float16 f16x8 __attribute__((ext_vector_type(8)));
typedef float    f32x4 __attribute__((ext_vector_type(4)));

#define MFMA16(A,B,C) __builtin_amdgcn_mfma_f32_16x16x32_f16((A),(B),(C),0,0,0)

static __device__ __forceinline__ f16x8 cat8(f16x4 a, f16x4 b) {
    return __builtin_shufflevector(a, b, 0, 1, 2, 3, 4, 5, 6, 7);
}
static __device__ __forceinline__ f16x8 lds8(const _Float16* p) {
    f16x4 a = *(const f16x4*)p;          // 8B-aligned ds_read_b64 pair
    f16x4 b = *(const f16x4*)(p + 4);
    return cat8(a, b);
}
// write-visibility barrier: my LDS writes drained, then rendezvous (no vmcnt drain)
static __device__ __forceinline__ void bar_w() {
    asm volatile("s_waitcnt lgkmcnt(0)" ::: "memory");
    __builtin_amdgcn_sched_barrier(0);
    __builtin_amdgcn_s_barrier();
    __builtin_amdgcn_sched_barrier(0);
    asm volatile("" ::: "memory");
}

__global__ __launch_bounds__(256, 2)
void sdpa_kernel(const float* __restrict__ Qg, const float* __restrict__ Kg,
                 const float* __restrict__ Vg, float* __restrict__ Og,
                 float* __restrict__ Ag)
{
    const int tid  = threadIdx.x;
    const int w    = tid >> 6;
    const int lane = tid & 63;
    const int lg   = lane >> 4;
    const int lc   = lane & 15;

    // XCD-pinned decode (proven: FETCH 103->12 MB): bid&7 = XCD, 2 heads per XCD.
    const int bid = blockIdx.x;
    const int xcd = bid & 7;
    const int j   = bid >> 3;           // 0..63
    const int bh  = 2 * xcd + (j >> 5); // 0..15
    const int qt  = j & 31;             // 0..31

    const size_t base = (size_t)bh * NS * ND;
    const float* Qp = Qg + base + (size_t)qt * QBLK * ND;
    const float* Kp = Kg + base;
    const float* Vp = Vg + base;
    float*       Op = Og + base + (size_t)qt * QBLK * ND;
    float*       Ap = Ag + (size_t)bh * NS * NS + (size_t)qt * QBLK * NS;

    // pool: Ks 19456 | VT 17920 | union(Qs 9728, Ps 16896) = 54272 B
    __shared__ __align__(16) unsigned char pool[54272];
    _Float16* Ks = (_Float16*)pool;
    _Float16* VT = (_Float16*)(pool + 19456);
    _Float16* Qs = (_Float16*)(pool + 37376);   // dead after qf loads
    _Float16* Ps = (_Float16*)(pool + 37376);   // overlays Qs in pass B

    const int srow = tid >> 4;          // 0..15
    const int sd0  = (tid & 15) * 4;    // 0..60
    const int kq   = tid >> 3;          // 0..31  (V: 4-key quad)
    const int dg   = tid & 7;           // 0..7   (V: 8-d group)

    // ---- stage Q (scaled by 1/T = 1/8, exact) ----
    #pragma unroll
    for (int it = 0; it < 4; ++it) {
        const int r = srow + 16 * it;
        float4 f = *(const float4*)&Qp[(size_t)r * ND + sd0];
        f16x4 h = { (_Float16)(f.x * 0.125f), (_Float16)(f.y * 0.125f),
                    (_Float16)(f.z * 0.125f), (_Float16)(f.w * 0.125f) };
        *(f16x4*)&Qs[r * QST + sd0] = h;
    }
    __syncthreads();

    const int q = 16 * w + lc;
    const f16x8 qf0 = lds8(&Qs[q * QST + 8 * lg]);
    const f16x8 qf1 = lds8(&Qs[q * QST + 8 * lg + 32]);

    float4 kreg[8];
    auto loadK = [&](int t) {
        #pragma unroll
        for (int it = 0; it < 8; ++it)
            kreg[it] = *(const float4*)&Kp[(size_t)(t * KBLK + srow + 16 * it) * ND + sd0];
    };
    auto writeK = [&]() {
        #pragma unroll
        for (int it = 0; it < 8; ++it) {
            f16x4 h = { (_Float16)kreg[it].x, (_Float16)kreg[it].y,
                        (_Float16)kreg[it].z, (_Float16)kreg[it].w };
            *(f16x4*)&Ks[(srow + 16 * it) * KST + sd0] = h;
        }
    };

    float lacc = 0.0f;   // max-free softmax: per-lane partial sum of exp(s)

    // ================= PASS A: denominator =================
    loadK(0);
    for (int t = 0; t < NKT; ++t) {
        writeK();
        loadK(t + 1 < NKT ? t + 1 : 0);
        bar_w();                       // all waves' K writes visible

        __builtin_amdgcn_s_setprio(1);
        f32x4 s[8];
        #pragma unroll
        for (int mt = 0; mt < 8; ++mt) {
            f16x8 a0 = lds8(&Ks[(16 * mt + lc) * KST + 8 * lg]);
            f16x8 a1 = lds8(&Ks[(16 * mt + lc) * KST + 8 * lg + 32]);
            f32x4 z = {0.f, 0.f, 0.f, 0.f};
            z = MFMA16(a0, qf0, z);
            z = MFMA16(a1, qf1, z);
            s[mt] = z;
        }
        __builtin_amdgcn_s_setprio(0);
        #pragma unroll
        for (int mt = 0; mt < 8; ++mt)
            #pragma unroll
            for (int r = 0; r < 4; ++r)
                lacc += __expf(s[mt][r]);

        bar_w();                       // all waves done reading Ks
    }
    lacc += __shfl_xor(lacc, 16);
    lacc += __shfl_xor(lacc, 32);
    const float il = 1.0f / lacc;

    // ================= PASS B: attn write + PV =================
    f32x4 acc[4];
    #pragma unroll
    for (int dt = 0; dt < 4; ++dt) acc[dt] = {0.f, 0.f, 0.f, 0.f};

    {
        float4 vreg[8];
        auto loadV = [&](int t) {   // thread owns keys 4kq..4kq+3 x d 8dg..8dg+7
            #pragma unroll
            for (int r = 0; r < 4; ++r)
                #pragma unroll
                for (int h = 0; h < 2; ++h)
                    vreg[2 * r + h] = *(const float4*)
                        &Vp[(size_t)(t * KBLK + 4 * kq + r) * ND + 8 * dg + 4 * h];
        };
        auto writeVT = [&]() {      // in-register 4x4 transpose -> b64 writes
            #pragma unroll
            for (int h = 0; h < 2; ++h)
                #pragma unroll
                for (int jj = 0; jj < 4; ++jj) {
                    f16x4 col = { (_Float16)vreg[0 + h][jj], (_Float16)vreg[2 + h][jj],
                                  (_Float16)vreg[4 + h][jj], (_Float16)vreg[6 + h][jj] };
                    *(f16x4*)&VT[(8 * dg + 4 * h + jj) * VST + 4 * kq] = col;
                }
        };

        loadK(0); loadV(0);
        for (int t = 0; t < NKT; ++t) {
            writeK(); writeVT();
            const int nt = t + 1 < NKT ? t + 1 : 0;
            loadK(nt); loadV(nt);
            bar_w();                   // all waves' K/VT writes visible

            // per-mt fused: QK^T -> p -> attn store + P stash (low VGPR pressure)
            #pragma unroll
            for (int mt = 0; mt < 8; ++mt) {
                f16x8 a0 = lds8(&Ks[(16 * mt + lc) * KST + 8 * lg]);
                f16x8 a1 = lds8(&Ks[(16 * mt + lc) * KST + 8 * lg + 32]);
                f32x4 z = {0.f, 0.f, 0.f, 0.f};
                __builtin_amdgcn_s_setprio(1);
                z = MFMA16(a0, qf0, z);
                z = MFMA16(a1, qf1, z);
                __builtin_amdgcn_s_setprio(0);
                f32x4 p;
                #pragma unroll
                for (int r = 0; r < 4; ++r)
                    p[r] = __expf(z[r]) * il;
                __builtin_nontemporal_store(
                    p, (f32x4*)&Ap[(size_t)q * NS + t * KBLK + 16 * mt + 4 * lg]);
                f16x4 ph = { (_Float16)p[0], (_Float16)p[1],
                             (_Float16)p[2], (_Float16)p[3] };
                *(f16x4*)&Ps[q * PST + 16 * mt + 4 * lg] = ph;
            }
            asm volatile("s_waitcnt lgkmcnt(0)" ::: "memory");  // wave-private P rows
            __builtin_amdgcn_sched_barrier(0);

            // PV: O^T += V^T . P^T  (4 k-slices of 32)
            f16x8 bf[4];
            #pragma unroll
            for (int ks = 0; ks < 4; ++ks)
                bf[ks] = lds8(&Ps[q * PST + 32 * ks + 8 * lg]);
            __builtin_amdgcn_s_setprio(1);
            #pragma unroll
            for (int dt = 0; dt < 4; ++dt) {
                #pragma unroll
                for (int ks = 0; ks < 4; ++ks) {
                    f16x8 af = lds8(&VT[(16 * dt + lc) * VST + 32 * ks + 8 * lg]);
                    acc[dt] = MFMA16(af, bf[ks], acc[dt]);
                }
            }
            __builtin_amdgcn_s_setprio(0);

            bar_w();                   // all waves done reading Ks/VT/Ps
        }
    }

    // O^T[d = 16dt+4lg+r][q] -> Op[q][d]
    #pragma unroll
    for (int dt = 0; dt < 4; ++dt)
        __builtin_nontemporal_store(
            acc[dt], (f32x4*)&Op[(size_t)q * ND + 16 * dt + 4 * lg]);
}

extern "C" void kernel_launch(void* const* d_in, const int* in_sizes, int n_in,
                              void* d_out, int out_size, void* d_ws, size_t ws_size,
                              hipStream_t stream) {
    const float* q = (const float*)d_in[0];
    const float* k = (const float*)d_in[1];
    const float* v = (const float*)d_in[2];
    float* out  = (float*)d_out;
    float* attn = out + (size_t)NB * NH * NS * ND;  // outputs: (output, attn)

    sdpa_kernel<<<dim3((NS / QBLK) * NB * NH), 256, 0, stream>>>(q, k, v, out, attn);
}

// Round 10
// 105.879 us; speedup vs baseline: 1.5812x; 1.0439x over previous
//
#include <hip/hip_runtime.h>

#define NB 2
#define NH 8
#define NS 2048
#define ND 64
#define WKT 32              // keys per wave-tile
#define NTW 16              // tiles per wave per pass (2048 / (32*4))
#define QST 68              // LDS strides (f16 elems; all rows 8B-aligned)
#define KST 76
#define VST 36
#define PST 36
#define OST 68              // f32

typedef _Float16 f16x4 __attribute__((ext_vector_type(4)));
typedef _Float16 f16x8 __attribute__((ext_vector_type(8)));
typedef float    f32x4 __attribute__((ext_vector_type(4)));

#define MFMA16(A,B,C) __builtin_amdgcn_mfma_f32_16x16x32_f16((A),(B),(C),0,0,0)

static __device__ __forceinline__ f16x8 cat8(f16x4 a, f16x4 b) {
    return __builtin_shufflevector(a, b, 0, 1, 2, 3, 4, 5, 6, 7);
}
static __device__ __forceinline__ f16x8 lds8(const _Float16* p) {
    f16x4 a = *(const f16x4*)p;          // ds_read_b64 pair
    f16x4 b = *(const f16x4*)(p + 4);
    return cat8(a, b);
}
// wave-local staging fence: wait own LDS ops, block DS reordering only
// (0x7F = allow ALU/VALU/SALU/MFMA/VMEM to cross; DS pinned)
static __device__ __forceinline__ void dsfence() {
    asm volatile("s_waitcnt lgkmcnt(0)");
    __builtin_amdgcn_sched_barrier(0x7F);
}

__global__ __launch_bounds__(256, 2)
void sdpa_kernel(const float* __restrict__ Qg, const float* __restrict__ Kg,
                 const float* __restrict__ Vg, float* __restrict__ Og,
                 float* __restrict__ Ag)
{
    const int tid  = threadIdx.x;
    const int w    = tid >> 6;
    const int lane = tid & 63;
    const int lg   = lane >> 4;
    const int lc   = lane & 15;

    // XCD-pinned decode (proven: FETCH 103->12 MB): bid&7 = XCD, 2 heads per XCD.
    const int bid = blockIdx.x;
    const int xcd = bid & 7;
    const int j   = bid >> 3;           // 0..63
    const int bh  = 2 * xcd + (j >> 5); // 0..15
    const int qt_ = j & 31;             // 0..31

    const size_t base = (size_t)bh * NS * ND;
    const float* Qp = Qg + base + (size_t)qt_ * 64 * ND;
    const float* Kp = Kg + base;
    const float* Vp = Vg + base;
    float*       Op = Og + base + (size_t)qt_ * 64 * ND;
    float*       Ap = Ag + (size_t)bh * NS * NS + (size_t)qt_ * 64 * NS;

    // wave-private regions: Ks[w] 4864 | VT[w] 4608 | Ps[w] 4608; prologue Qs
    // and epilogue Obuf overlay the Ks region; MLs overlays Ps. Total 56320 B.
    __shared__ __align__(16) unsigned char pool[56320];
    _Float16* Qs = (_Float16*)pool;                            // prologue only
    _Float16* Ks = (_Float16*)(pool + (size_t)w * 4864);
    _Float16* VT = (_Float16*)(pool + 19456 + (size_t)w * 4608);
    _Float16* Ps = (_Float16*)(pool + 37888 + (size_t)w * 4608);
    float*   MLs = (float*)(pool + 37888);                     // inter-pass
    float*  Obuf = (float*)pool;                               // epilogue

    // ---- stage Q (scaled by 1/T = 1/8, exact) cooperatively ----
    {
        const int srow = tid >> 4, sd0 = (tid & 15) * 4;
        #pragma unroll
        for (int it = 0; it < 4; ++it) {
            const int r = srow + 16 * it;
            float4 f = *(const float4*)&Qp[(size_t)r * ND + sd0];
            f16x4 h = { (_Float16)(f.x * 0.125f), (_Float16)(f.y * 0.125f),
                        (_Float16)(f.z * 0.125f), (_Float16)(f.w * 0.125f) };
            *(f16x4*)&Qs[r * QST + sd0] = h;
        }
    }
    __syncthreads();
    f16x8 qfa[4], qfb[4];        // every wave needs all 64 q columns
    #pragma unroll
    for (int qt = 0; qt < 4; ++qt) {
        qfa[qt] = lds8(&Qs[(16 * qt + lc) * QST + 8 * lg]);
        qfb[qt] = lds8(&Qs[(16 * qt + lc) * QST + 8 * lg + 32]);
    }
    __syncthreads();             // Qs dead; Ks overlays it

    const int vkq = lane >> 3;   // V staging: key quad 4*vkq
    const int vdg = lane & 7;    // V staging: d group 8*vdg

    float lacc[4] = {0.f, 0.f, 0.f, 0.f};

    // ============ PASS A: denominators (wave-private, barrier-free) ============
    for (int t = 0; t < NTW; ++t) {
        const int koff = (4 * t + w) * WKT;
        {
            float4 kr[8];        // flat-coalesced: 1 KB per instruction
            #pragma unroll
            for (int i = 0; i < 8; ++i)
                kr[i] = *(const float4*)&Kp[(size_t)koff * ND + i * 256 + 4 * lane];
            #pragma unroll
            for (int i = 0; i < 8; ++i) {
                f16x4 h = { (_Float16)kr[i].x, (_Float16)kr[i].y,
                            (_Float16)kr[i].z, (_Float16)kr[i].w };
                *(f16x4*)&Ks[(4 * i + lg) * KST + 4 * lc] = h;
            }
        }
        dsfence();

        __builtin_amdgcn_s_setprio(1);
        #pragma unroll
        for (int mt = 0; mt < 2; ++mt) {
            f16x8 a0 = lds8(&Ks[(16 * mt + lc) * KST + 8 * lg]);
            f16x8 a1 = lds8(&Ks[(16 * mt + lc) * KST + 8 * lg + 32]);
            #pragma unroll
            for (int qt = 0; qt < 4; ++qt) {
                f32x4 z = {0.f, 0.f, 0.f, 0.f};
                z = MFMA16(a0, qfa[qt], z);
                z = MFMA16(a1, qfb[qt], z);
                #pragma unroll
                for (int r = 0; r < 4; ++r)
                    lacc[qt] += __expf(z[r]);
            }
        }
        __builtin_amdgcn_s_setprio(0);
        __builtin_amdgcn_sched_barrier(0x7F);   // reads stay before next writes
    }

    // ---- merge denominators across waves (max-free softmax) ----
    #pragma unroll
    for (int qt = 0; qt < 4; ++qt) {
        lacc[qt] += __shfl_xor(lacc[qt], 16);
        lacc[qt] += __shfl_xor(lacc[qt], 32);
    }
    if (lg == 0) {
        #pragma unroll
        for (int qt = 0; qt < 4; ++qt)
            MLs[w * 64 + 16 * qt + lc] = lacc[qt];
    }
    __syncthreads();
    float il[4];
    #pragma unroll
    for (int qt = 0; qt < 4; ++qt)
        il[qt] = 1.0f / (MLs[16 * qt + lc] + MLs[64 + 16 * qt + lc] +
                         MLs[128 + 16 * qt + lc] + MLs[192 + 16 * qt + lc]);
    __syncthreads();             // MLs dead; Ps overlays it

    // ============ PASS B: attn write + PV (wave-private, barrier-free) ============
    f32x4 acc[4][4];             // [dt][qt] : O^T partials for this wave's keys
    #pragma unroll
    for (int dt = 0; dt < 4; ++dt)
        #pragma unroll
        for (int qt = 0; qt < 4; ++qt)
            acc[dt][qt] = {0.f, 0.f, 0.f, 0.f};

    for (int t = 0; t < NTW; ++t) {
        const int koff = (4 * t + w) * WKT;
        {
            float4 kr[8];
            #pragma unroll
            for (int i = 0; i < 8; ++i)
                kr[i] = *(const float4*)&Kp[(size_t)koff * ND + i * 256 + 4 * lane];
            #pragma unroll
            for (int i = 0; i < 8; ++i) {
                f16x4 h = { (_Float16)kr[i].x, (_Float16)kr[i].y,
                            (_Float16)kr[i].z, (_Float16)kr[i].w };
                *(f16x4*)&Ks[(4 * i + lg) * KST + 4 * lc] = h;
            }
        }
        {
            float4 vr[8];        // keys 4vkq..+3  x  d 8vdg..+7
            #pragma unroll
            for (int r = 0; r < 4; ++r)
                #pragma unroll
                for (int h = 0; h < 2; ++h)
                    vr[2 * r + h] = *(const float4*)
                        &Vp[(size_t)(koff + 4 * vkq + r) * ND + 8 * vdg + 4 * h];
            #pragma unroll
            for (int h = 0; h < 2; ++h)
                #pragma unroll
                for (int jj = 0; jj < 4; ++jj) {   // 4x4 in-register transpose
                    f16x4 col = { (_Float16)vr[0 + h][jj], (_Float16)vr[2 + h][jj],
                                  (_Float16)vr[4 + h][jj], (_Float16)vr[6 + h][jj] };
                    *(f16x4*)&VT[(8 * vdg + 4 * h + jj) * VST + 4 * vkq] = col;
                }
        }
        dsfence();

        f32x4 s[2][4];
        __builtin_amdgcn_s_setprio(1);
        #pragma unroll
        for (int mt = 0; mt < 2; ++mt) {
            f16x8 a0 = lds8(&Ks[(16 * mt + lc) * KST + 8 * lg]);
            f16x8 a1 = lds8(&Ks[(16 * mt + lc) * KST + 8 * lg + 32]);
            #pragma unroll
            for (int qt = 0; qt < 4; ++qt) {
                f32x4 z = {0.f, 0.f, 0.f, 0.f};
                z = MFMA16(a0, qfa[qt], z);
                z = MFMA16(a1, qfb[qt], z);
                s[mt][qt] = z;
            }
        }
        __builtin_amdgcn_s_setprio(0);

        #pragma unroll
        for (int mt = 0; mt < 2; ++mt)
            #pragma unroll
            for (int qt = 0; qt < 4; ++qt) {
                f32x4 p;
                #pragma unroll
                for (int r = 0; r < 4; ++r)
                    p[r] = __expf(s[mt][qt][r]) * il[qt];
                __builtin_nontemporal_store(p,
                    (f32x4*)&Ap[(size_t)(16 * qt + lc) * NS + koff + 16 * mt + 4 * lg]);
                f16x4 ph = { (_Float16)p[0], (_Float16)p[1],
                             (_Float16)p[2], (_Float16)p[3] };
                *(f16x4*)&Ps[(16 * qt + lc) * PST + 16 * mt + 4 * lg] = ph;
            }
        dsfence();

        f16x8 bf[4];
        #pragma unroll
        for (int qt = 0; qt < 4; ++qt)
            bf[qt] = lds8(&Ps[(16 * qt + lc) * PST + 8 * lg]);
        __builtin_amdgcn_s_setprio(1);
        #pragma unroll
        for (int dt = 0; dt < 4; ++dt) {
            f16x8 af = lds8(&VT[(16 * dt + lc) * VST + 8 * lg]);
            #pragma unroll
            for (int qt = 0; qt < 4; ++qt)
                acc[dt][qt] = MFMA16(af, bf[qt], acc[dt][qt]);
        }
        __builtin_amdgcn_s_setprio(0);
        __builtin_amdgcn_sched_barrier(0x7F);
    }

    // ---- merge partial O across waves (sequential LDS accumulate), store ----
    __syncthreads();             // all main-loop LDS dead; Obuf overlays
    #pragma unroll
    for (int ww = 0; ww < 4; ++ww) {
        if (w == ww) {
            #pragma unroll
            for (int dt = 0; dt < 4; ++dt)
                #pragma unroll
                for (int qt = 0; qt < 4; ++qt) {
                    float* ad = &Obuf[(16 * qt + lc) * OST + 16 * dt + 4 * lg];
                    f32x4 v = acc[dt][qt];
                    if (ww > 0) v = v + *(const f32x4*)ad;
                    *(f32x4*)ad = v;
                }
        }
        __syncthreads();
    }
    #pragma unroll
    for (int dt = 0; dt < 4; ++dt) {
        f32x4 o = *(const f32x4*)&Obuf[(16 * w + lc) * OST + 16 * dt + 4 * lg];
        __builtin_nontemporal_store(o,
            (f32x4*)&Op[(size_t)(16 * w + lc) * ND + 16 * dt + 4 * lg]);
    }
}

extern "C" void kernel_launch(void* const* d_in, const int* in_sizes, int n_in,
                              void* d_out, int out_size, void* d_ws, size_t ws_size,
                              hipStream_t stream) {
    const float* q = (const float*)d_in[0];
    const float* k = (const float*)d_in[1];
    const float* v = (const float*)d_in[2];
    float* out  = (float*)d_out;
    float* attn = out + (size_t)NB * NH * NS * ND;  // outputs: (output, attn)

    sdpa_kernel<<<dim3((NS / 64) * NB * NH), 256, 0, stream>>>(q, k, v, out, attn);
}